// Round 1
// baseline (990.231 us; speedup 1.0000x reference)
//
#include <hip/hip_runtime.h>

// ---------------------------------------------------------------------------
// NeighborEmbedder: patch-embed + 9-token transformer block on MI355X (gfx950)
// Round 1: full pipeline, bf16 MFMA GEMMs (128x128 tile, m97-style staging),
// fused per-sample attention, wave-per-row LayerNorm.
// ---------------------------------------------------------------------------

typedef unsigned short u16;
typedef u16   u16x8 __attribute__((ext_vector_type(8)));
typedef u16   u16x4 __attribute__((ext_vector_type(4)));
typedef __bf16 bf16x8 __attribute__((ext_vector_type(8)));
typedef float f32x4 __attribute__((ext_vector_type(4)));

static __device__ __forceinline__ u16 f2bf(float f) {
  union { float f; unsigned u; } v; v.f = f;
  unsigned r = v.u + 0x7FFFu + ((v.u >> 16) & 1u);   // RNE
  return (u16)(r >> 16);
}
static __device__ __forceinline__ float bf2f(u16 u) {
  union { unsigned u; float f; } v; v.u = ((unsigned)u) << 16;
  return v.f;
}

// async global->LDS, 16B per lane. LDS dest must be wave-uniform.
static __device__ __forceinline__ void gld16(const void* g, void* l) {
  __builtin_amdgcn_global_load_lds(
      (__attribute__((address_space(1))) unsigned int*)(size_t)g,
      (__attribute__((address_space(3))) unsigned int*)(unsigned)(size_t)l,
      16, 0, 0);
}

// ---------------------------------------------------------------------------
// Generic GEMM: out[M,N](bf16) = A[M,K] @ W[N,K]^T + bias (+pos / +res / gelu)
// A: bf16 (lda element stride) or f32 (A_F32, converted during staging).
// 128x128 block tile, BK=32, 4 waves each computing a 64x64 sub-tile of
// 4x4 mfma_f32_16x16x32_bf16 fragments.
// ---------------------------------------------------------------------------
template<bool A_F32, bool HAS_POS, bool HAS_RES, bool HAS_GELU>
__global__ __launch_bounds__(256) void gemm_k(
    const void* Av, int lda,
    const u16* __restrict__ W,
    const float* __restrict__ bias,
    const float* __restrict__ pos,
    const u16* res, int res_stride,
    u16* out,
    int M, int N, int K)
{
  __shared__ u16 As[128 * 32];
  __shared__ u16 Bs[128 * 32];
  const int t    = threadIdx.x;
  const int lane = t & 63, wv = t >> 6;
  const int bm   = blockIdx.y * 128, bn = blockIdx.x * 128;
  const int wr   = wv >> 1, wc = wv & 1;          // wave -> 64x64 sub-tile

  f32x4 acc[4][4] = {};

  const int srow = lane >> 2;          // row within a 16-row staging chunk
  const int skk  = (lane & 3) * 8;     // k offset (8 bf16 = 16B per lane)

  for (int k0 = 0; k0 < K; k0 += 32) {
    __syncthreads();                    // previous tile fully consumed
    if constexpr (A_F32) {
      const float* A = (const float*)Av;
      #pragma unroll
      for (int i = 0; i < 4; ++i) {
        int idx = i * 256 + t;          // float4 index within 128x32 tile
        int r = idx >> 3, c4 = (idx & 7) * 4;
        float4 f = *(const float4*)(A + (size_t)(bm + r) * lda + k0 + c4);
        u16x4 o; o.x = f2bf(f.x); o.y = f2bf(f.y); o.z = f2bf(f.z); o.w = f2bf(f.w);
        *(u16x4*)&As[r * 32 + c4] = o;
      }
    } else {
      const u16* A = (const u16*)Av;
      gld16(A + (size_t)(bm + wv * 16 + srow) * lda + k0 + skk, &As[wv * 512]);
      gld16(A + (size_t)(bm + (wv + 4) * 16 + srow) * lda + k0 + skk, &As[(wv + 4) * 512]);
    }
    gld16(W + (size_t)(bn + wv * 16 + srow) * K + k0 + skk, &Bs[wv * 512]);
    gld16(W + (size_t)(bn + (wv + 4) * 16 + srow) * K + k0 + skk, &Bs[(wv + 4) * 512]);
    __syncthreads();                    // waits vmcnt+lgkmcnt (compiler)

    const int lr = lane & 15, lk = (lane >> 4) * 8;
    bf16x8 a[4], b[4];
    #pragma unroll
    for (int m = 0; m < 4; ++m)
      a[m] = *(const bf16x8*)&As[(wr * 64 + m * 16 + lr) * 32 + lk];
    #pragma unroll
    for (int n = 0; n < 4; ++n)
      b[n] = *(const bf16x8*)&Bs[(wc * 64 + n * 16 + lr) * 32 + lk];
    #pragma unroll
    for (int m = 0; m < 4; ++m)
      #pragma unroll
      for (int n = 0; n < 4; ++n)
        acc[m][n] = __builtin_amdgcn_mfma_f32_16x16x32_bf16(a[m], b[n], acc[m][n], 0, 0, 0);
  }

  // epilogue: C[row][col], row = (lane>>4)*4 + reg, col = lane&15 (m89 layout)
  const int lr = lane & 15, lq = lane >> 4;
  #pragma unroll
  for (int m = 0; m < 4; ++m) {
    #pragma unroll
    for (int n = 0; n < 4; ++n) {
      int col = bn + wc * 64 + n * 16 + lr;
      float bv = bias[col];
      #pragma unroll
      for (int r = 0; r < 4; ++r) {
        int row = bm + wr * 64 + m * 16 + lq * 4 + r;
        float v = acc[m][n][r] + bv;
        if constexpr (HAS_POS) v += pos[(row % 9) * 512 + col];
        if constexpr (HAS_RES) v += bf2f(res[(size_t)row * res_stride + col]);
        if constexpr (HAS_GELU) v = 0.5f * v * (1.f + erff(v * 0.70710678118f));
        out[(size_t)row * N + col] = f2bf(v);
      }
    }
  }
}

// ---------------------------------------------------------------------------
// LayerNorm over rows of 512 (bf16 in). One wave per row, 4 rows per block.
// ---------------------------------------------------------------------------
__global__ __launch_bounds__(256) void ln_k(
    const u16* in,
    const float* __restrict__ g, const float* __restrict__ be,
    u16* out_bf, float* out_f32, int rows)
{
  int wv = threadIdx.x >> 6, lane = threadIdx.x & 63;
  int row = blockIdx.x * 4 + wv;
  if (row >= rows) return;
  const u16* p = in + (size_t)row * 512;
  u16x8 v = *(const u16x8*)&p[lane * 8];
  float x[8], s = 0.f, sq = 0.f;
  #pragma unroll
  for (int j = 0; j < 8; ++j) { x[j] = bf2f(v[j]); s += x[j]; sq += x[j] * x[j]; }
  #pragma unroll
  for (int o = 32; o > 0; o >>= 1) { s += __shfl_xor(s, o, 64); sq += __shfl_xor(sq, o, 64); }
  float mean = s * (1.f / 512.f);
  float var  = sq * (1.f / 512.f) - mean * mean;
  float rs   = rsqrtf(var + 1e-5f);
  float y[8];
  #pragma unroll
  for (int j = 0; j < 8; ++j) {
    int c = lane * 8 + j;
    y[j] = (x[j] - mean) * rs * g[c] + be[c];
  }
  if (out_bf) {
    u16x8 o8;
    #pragma unroll
    for (int j = 0; j < 8; ++j) o8[j] = f2bf(y[j]);
    *(u16x8*)&out_bf[(size_t)row * 512 + lane * 8] = o8;
  }
  if (out_f32) {
    #pragma unroll
    for (int j = 0; j < 8; ++j) out_f32[(size_t)row * 512 + lane * 8 + j] = y[j];
  }
}

// ---------------------------------------------------------------------------
// Self-attention, one block per sample: qkv[9,1536] (q|k|v), H=8, d=64, L=9.
// ---------------------------------------------------------------------------
__global__ __launch_bounds__(256) void sa_attn_k(const u16* __restrict__ qkv,
                                                 u16* __restrict__ out)
{
  __shared__ u16  s_qkv[9 * 1536];
  __shared__ float s_sc[8][81];
  const int s = blockIdx.x, t = threadIdx.x;
  const u16* src = qkv + (size_t)s * 9 * 1536;
  for (int i = t; i < (9 * 1536) / 8; i += 256)
    *(u16x8*)&s_qkv[i * 8] = *(const u16x8*)&src[i * 8];
  __syncthreads();

  const int h = t >> 5, sl = t & 31;
  for (int p = sl; p < 81; p += 32) {
    int qi = p / 9, ki = p % 9;
    const u16* qp = &s_qkv[qi * 1536 + h * 64];
    const u16* kp = &s_qkv[ki * 1536 + 512 + h * 64];
    float d = 0.f;
    #pragma unroll
    for (int e8 = 0; e8 < 8; ++e8) {
      u16x8 qv = *(const u16x8*)&qp[e8 * 8];
      u16x8 kv = *(const u16x8*)&kp[e8 * 8];
      #pragma unroll
      for (int j = 0; j < 8; ++j) d += bf2f(qv[j]) * bf2f(kv[j]);
    }
    s_sc[h][p] = d * 0.125f;
  }
  __syncthreads();

  if (t < 72) {
    int hh = t / 9, qi = t % 9;
    float* sc = &s_sc[hh][qi * 9];
    float mx = sc[0];
    #pragma unroll
    for (int i = 1; i < 9; ++i) mx = fmaxf(mx, sc[i]);
    float e[9], sum = 0.f;
    #pragma unroll
    for (int i = 0; i < 9; ++i) { e[i] = __expf(sc[i] - mx); sum += e[i]; }
    float inv = 1.f / sum;
    #pragma unroll
    for (int i = 0; i < 9; ++i) sc[i] = e[i] * inv;
  }
  __syncthreads();

  for (int gidx = sl; gidx < 72; gidx += 32) {   // 9 qi x 8 d-groups
    int qi = gidx >> 3, dg = gidx & 7;
    float a[8] = {};
    #pragma unroll
    for (int ki = 0; ki < 9; ++ki) {
      float pr = s_sc[h][qi * 9 + ki];
      u16x8 vv = *(const u16x8*)&s_qkv[ki * 1536 + 1024 + h * 64 + dg * 8];
      #pragma unroll
      for (int j = 0; j < 8; ++j) a[j] += pr * bf2f(vv[j]);
    }
    u16x8 o8;
    #pragma unroll
    for (int j = 0; j < 8; ++j) o8[j] = f2bf(a[j]);
    *(u16x8*)&out[((size_t)s * 9 + qi) * 512 + h * 64 + dg * 8] = o8;
  }
}

// ---------------------------------------------------------------------------
// Cross-attention, one block per sample: q[512], kv[9,1024] (k|v).
// ---------------------------------------------------------------------------
__global__ __launch_bounds__(256) void ca_attn_k(const u16* __restrict__ q,
                                                 const u16* __restrict__ kv,
                                                 u16* __restrict__ out)
{
  __shared__ u16  s_q[512];
  __shared__ u16  s_kv[9 * 1024];
  __shared__ float s_sc[8][9];
  const int s = blockIdx.x, t = threadIdx.x;
  if (t < 64) *(u16x8*)&s_q[t * 8] = *(const u16x8*)&q[(size_t)s * 512 + t * 8];
  for (int i = t; i < (9 * 1024) / 8; i += 256)
    *(u16x8*)&s_kv[i * 8] = *(const u16x8*)&kv[(size_t)s * 9 * 1024 + i * 8];
  __syncthreads();

  if (t < 72) {
    int h = t / 9, ki = t % 9;
    const u16* qp = &s_q[h * 64];
    const u16* kp = &s_kv[ki * 1024 + h * 64];
    float d = 0.f;
    #pragma unroll
    for (int e8 = 0; e8 < 8; ++e8) {
      u16x8 qv = *(const u16x8*)&qp[e8 * 8];
      u16x8 kvv = *(const u16x8*)&kp[e8 * 8];
      #pragma unroll
      for (int j = 0; j < 8; ++j) d += bf2f(qv[j]) * bf2f(kvv[j]);
    }
    s_sc[h][ki] = d * 0.125f;
  }
  __syncthreads();

  if (t < 8) {
    float* sc = s_sc[t];
    float mx = sc[0];
    #pragma unroll
    for (int i = 1; i < 9; ++i) mx = fmaxf(mx, sc[i]);
    float e[9], sum = 0.f;
    #pragma unroll
    for (int i = 0; i < 9; ++i) { e[i] = __expf(sc[i] - mx); sum += e[i]; }
    float inv = 1.f / sum;
    #pragma unroll
    for (int i = 0; i < 9; ++i) sc[i] = e[i] * inv;
  }
  __syncthreads();

  if (t < 64) {
    int h = t >> 3, dg = t & 7;
    float a[8] = {};
    #pragma unroll
    for (int ki = 0; ki < 9; ++ki) {
      float pr = s_sc[h][ki];
      u16x8 vv = *(const u16x8*)&s_kv[ki * 1024 + 512 + h * 64 + dg * 8];
      #pragma unroll
      for (int j = 0; j < 8; ++j) a[j] += pr * bf2f(vv[j]);
    }
    u16x8 o8;
    #pragma unroll
    for (int j = 0; j < 8; ++j) o8[j] = f2bf(a[j]);
    *(u16x8*)&out[(size_t)s * 512 + h * 64 + dg * 8] = o8;
  }
}

// f32 -> bf16 conversion (weights). n % 4 == 0.
__global__ __launch_bounds__(256) void cvt_k(const float* __restrict__ in,
                                             u16* __restrict__ out, int n)
{
  int i = (blockIdx.x * 256 + threadIdx.x) * 4;
  if (i >= n) return;
  float4 f = *(const float4*)&in[i];
  u16x4 o; o.x = f2bf(f.x); o.y = f2bf(f.y); o.z = f2bf(f.z); o.w = f2bf(f.w);
  *(u16x4*)&out[i] = o;
}

// ---------------------------------------------------------------------------
// Host launcher
// ---------------------------------------------------------------------------
extern "C" void kernel_launch(void* const* d_in, const int* in_sizes, int n_in,
                              void* d_out, int out_size, void* d_ws, size_t ws_size,
                              hipStream_t stream)
{
  const float* patches  = (const float*)d_in[0];
  const float* w_pe     = (const float*)d_in[1];
  const float* b_pe     = (const float*)d_in[2];
  const float* pos      = (const float*)d_in[3];
  const float* sa_in_w  = (const float*)d_in[4];
  const float* sa_in_b  = (const float*)d_in[5];
  const float* sa_out_w = (const float*)d_in[6];
  const float* sa_out_b = (const float*)d_in[7];
  const float* g1       = (const float*)d_in[8];
  const float* beta1    = (const float*)d_in[9];
  const float* ca_in_w  = (const float*)d_in[10];
  const float* ca_in_b  = (const float*)d_in[11];
  const float* ca_out_w = (const float*)d_in[12];
  const float* ca_out_b = (const float*)d_in[13];
  const float* g2       = (const float*)d_in[14];
  const float* beta2    = (const float*)d_in[15];
  const float* w1       = (const float*)d_in[16];
  const float* b1       = (const float*)d_in[17];
  const float* w2       = (const float*)d_in[18];
  const float* b2       = (const float*)d_in[19];
  const float* g3       = (const float*)d_in[20];
  const float* beta3    = (const float*)d_in[21];
  float* out = (float*)d_out;

  // workspace layout (bytes), ~433 MB total
  char* base = (char*)d_ws;
  u16* wbf        = (u16*)base;                       // 4,587,520 bf16 weights
  u16* w_pe_bf    = wbf;
  u16* sa_in_bf   = wbf + 393216;
  u16* sa_out_bf  = wbf + 1179648;
  u16* ca_in_bf   = wbf + 1441792;
  u16* ca_out_bf  = wbf + 2228224;
  u16* w1_bf      = wbf + 2490368;
  u16* w2_bf      = wbf + 3538944;
  u16* x_bf  = (u16*)(base + 9175040ull);     // [73728,512]  x / xsum / x1
  u16* qkv   = (u16*)(base + 84672512ull);    // [73728,1536] qkv, reused as CA kv
  u16* sattn = (u16*)(base + 311164928ull);   // [73728,512]
  u16* q_bf  = (u16*)(base + 386662400ull);   // [8192,512]
  u16* cattn = (u16*)(base + 395051008ull);   // [8192,512]
  u16* csum  = (u16*)(base + 403439616ull);   // [8192,512]  csum / c
  u16* h_bf  = (u16*)(base + 411828224ull);   // [8192,2048]
  u16* osum  = (u16*)(base + 445382656ull);   // [8192,512]

  // weights -> bf16
  cvt_k<<<393216 / 1024, 256, 0, stream>>>(w_pe, w_pe_bf, 393216);
  cvt_k<<<786432 / 1024, 256, 0, stream>>>(sa_in_w, sa_in_bf, 786432);
  cvt_k<<<262144 / 1024, 256, 0, stream>>>(sa_out_w, sa_out_bf, 262144);
  cvt_k<<<786432 / 1024, 256, 0, stream>>>(ca_in_w, ca_in_bf, 786432);
  cvt_k<<<262144 / 1024, 256, 0, stream>>>(ca_out_w, ca_out_bf, 262144);
  cvt_k<<<1048576 / 1024, 256, 0, stream>>>(w1, w1_bf, 1048576);
  cvt_k<<<1048576 / 1024, 256, 0, stream>>>(w2, w2_bf, 1048576);

  // 1. patch embed + bias + pos_embed  -> x_bf
  gemm_k<true, true, false, false><<<dim3(4, 576), 256, 0, stream>>>(
      patches, 768, w_pe_bf, b_pe, pos, nullptr, 0, x_bf, 73728, 512, 768);
  // 2. SA qkv
  gemm_k<false, false, false, false><<<dim3(12, 576), 256, 0, stream>>>(
      x_bf, 512, sa_in_bf, sa_in_b, nullptr, nullptr, 0, qkv, 73728, 1536, 512);
  // 3. SA attention
  sa_attn_k<<<8192, 256, 0, stream>>>(qkv, sattn);
  // 4. SA out proj + residual(x)  -> x_bf (in place, element-wise)
  gemm_k<false, false, true, false><<<dim3(4, 576), 256, 0, stream>>>(
      sattn, 512, sa_out_bf, sa_out_b, nullptr, x_bf, 512, x_bf, 73728, 512, 512);
  // 5. LN1 (in place)
  ln_k<<<73728 / 4, 256, 0, stream>>>(x_bf, g1, beta1, x_bf, nullptr, 73728);
  // 6. CA q from center token (row stride 9*512, offset 4*512)
  gemm_k<false, false, false, false><<<dim3(4, 64), 256, 0, stream>>>(
      x_bf + 2048, 4608, ca_in_bf, ca_in_b, nullptr, nullptr, 0, q_bf, 8192, 512, 512);
  // 7. CA kv (wk|wv = ca_in_w rows 512..1535)
  gemm_k<false, false, false, false><<<dim3(8, 576), 256, 0, stream>>>(
      x_bf, 512, ca_in_bf + 262144, ca_in_b + 512, nullptr, nullptr, 0, qkv, 73728, 1024, 512);
  // 8. CA attention
  ca_attn_k<<<8192, 256, 0, stream>>>(q_bf, qkv, cattn);
  // 9. CA out proj + residual(cq) -> csum
  gemm_k<false, false, true, false><<<dim3(4, 64), 256, 0, stream>>>(
      cattn, 512, ca_out_bf, ca_out_b, nullptr, x_bf + 2048, 4608, csum, 8192, 512, 512);
  // 10. LN2 (in place) -> c
  ln_k<<<8192 / 4, 256, 0, stream>>>(csum, g2, beta2, csum, nullptr, 8192);
  // 11. FFN1 + exact GELU -> h_bf
  gemm_k<false, false, false, true><<<dim3(16, 64), 256, 0, stream>>>(
      csum, 512, w1_bf, b1, nullptr, nullptr, 0, h_bf, 8192, 2048, 512);
  // 12. FFN2 + residual(c) -> osum
  gemm_k<false, false, true, false><<<dim3(4, 64), 256, 0, stream>>>(
      h_bf, 2048, w2_bf, b2, nullptr, csum, 512, osum, 8192, 512, 2048);
  // 13. LN3 -> d_out (f32)
  ln_k<<<8192 / 4, 256, 0, stream>>>(osum, g3, beta3, nullptr, out, 8192);
}